// Round 7
// baseline (206.026 us; speedup 1.0000x reference)
//
#include <hip/hip_runtime.h>

#define NODES 10000
#define BATCH 8
#define CH    128
#define KNB   16
#define CO    256

typedef __bf16 bf16x8 __attribute__((ext_vector_type(8)));
typedef float  f32x4  __attribute__((ext_vector_type(4)));

__device__ __forceinline__ unsigned short f2bf(float f) {
  unsigned u = __float_as_uint(f);
  u = (u + 0x7FFFu + ((u >> 16) & 1u)) >> 16;   // RNE
  return (unsigned short)u;
}
__device__ __forceinline__ unsigned pk2(float a, float b) {
  return (unsigned)f2bf(a) | ((unsigned)f2bf(b) << 16);
}
// max of packed non-negative bf16 == packed u16 max (relu guarantees >=0)
__device__ __forceinline__ unsigned pkmax(unsigned a, unsigned b) {
  unsigned d;
  asm("v_pk_max_u16 %0, %1, %2" : "=v"(d) : "v"(a), "v"(b));
  return d;
}
__device__ __forceinline__ uint4 pkmax4(uint4 a, uint4 b) {
  a.x = pkmax(a.x, b.x); a.y = pkmax(a.y, b.y);
  a.z = pkmax(a.z, b.z); a.w = pkmax(a.w, b.w);
  return a;
}
__device__ __forceinline__ bf16x8 asbf8(uint4 u) {
  union { uint4 u; bf16x8 b; } c; c.u = u; return c.b;
}

// ---------------------------------------------------------------------------
// fp32 -> bf16 weight conversion (row-major [d][k] kept)
// ---------------------------------------------------------------------------
__global__ __launch_bounds__(256) void prep(
    const float* __restrict__ W1, const float* __restrict__ Wp,
    const float* __restrict__ W2,
    unsigned short* __restrict__ W1b, unsigned short* __restrict__ Wpb,
    unsigned short* __restrict__ W2b)
{
  int i = blockIdx.x * 256 + threadIdx.x;   // float4 index, 24576 total
  const float* src; unsigned short* dst; int off;
  if (i < 4096)      { src = W1; dst = W1b; off = i; }
  else if (i < 8192) { src = Wp; dst = Wpb; off = i - 4096; }
  else               { src = W2; dst = W2b; off = i - 8192; }
  float4 v = ((const float4*)src)[off];
  ushort4 o;
  o.x = f2bf(v.x); o.y = f2bf(v.y); o.z = f2bf(v.z); o.w = f2bf(v.w);
  ((ushort4*)dst)[off] = o;
}

// ---------------------------------------------------------------------------
// Fused h = relu(W1 x + b1), z = relu(Wp h + bp), both bf16 [b][n][128].
// Wave-independent (no __syncthreads), 32 nodes/wave. (unchanged from R6)
// ---------------------------------------------------------------------------
__global__ __launch_bounds__(256) void fused_hz(
    const unsigned short* __restrict__ W1b, const float* __restrict__ b1,
    const unsigned short* __restrict__ Wpb, const float* __restrict__ bp,
    const float* __restrict__ x,
    unsigned short* __restrict__ h_t, unsigned short* __restrict__ z_t)
{
  const int b    = blockIdx.y;
  const int t    = threadIdx.x;
  const int w    = t >> 6, lane = t & 63;
  const int lm   = lane & 15, q = lane >> 4;
  const int nw0  = blockIdx.x * 128 + w * 32;

  __shared__ __align__(16) unsigned short Hs_all[4][32 * 128];  // 8KB/wave
  char* Hs = (char*)Hs_all[w];

  int node[2], gn[2];
  node[0] = nw0 + lm;      gn[0] = node[0] < NODES ? node[0] : NODES - 1;
  node[1] = nw0 + 16 + lm; gn[1] = node[1] < NODES ? node[1] : NODES - 1;

  // ---- x B-fragments to registers
  uint4 B1[2][4];
#pragma unroll
  for (int nt = 0; nt < 2; ++nt) {
    const float* X = x + (size_t)b * CH * NODES + gn[nt];
    float xv[32];
#pragma unroll
    for (int kt = 0; kt < 4; ++kt)
#pragma unroll
      for (int j = 0; j < 8; ++j)
        xv[kt * 8 + j] = X[(size_t)(kt * 32 + q * 8 + j) * NODES];
#pragma unroll
    for (int kt = 0; kt < 4; ++kt) {
      B1[nt][kt].x = pk2(xv[kt * 8 + 0], xv[kt * 8 + 1]);
      B1[nt][kt].y = pk2(xv[kt * 8 + 2], xv[kt * 8 + 3]);
      B1[nt][kt].z = pk2(xv[kt * 8 + 4], xv[kt * 8 + 5]);
      B1[nt][kt].w = pk2(xv[kt * 8 + 6], xv[kt * 8 + 7]);
    }
  }

  // ---- phase 1: h = relu(W1 x + b1)
  uint4 a[2][4];
#pragma unroll
  for (int kt = 0; kt < 4; ++kt) {
    a[0][kt] = *(const uint4*)(W1b + (size_t)(lm) * CH + kt * 32 + q * 8);
    a[1][kt] = *(const uint4*)(W1b + (size_t)(16 + lm) * CH + kt * 32 + q * 8);
  }
#pragma unroll
  for (int dt = 0; dt < 8; ++dt) {
    f32x4 acc0 = (f32x4){0.f, 0.f, 0.f, 0.f};
    f32x4 acc1 = (f32x4){0.f, 0.f, 0.f, 0.f};
#pragma unroll
    for (int kt = 0; kt < 4; ++kt) {
      acc0 = __builtin_amdgcn_mfma_f32_16x16x32_bf16(
          asbf8(a[dt & 1][kt]), asbf8(B1[0][kt]), acc0, 0, 0, 0);
      acc1 = __builtin_amdgcn_mfma_f32_16x16x32_bf16(
          asbf8(a[dt & 1][kt]), asbf8(B1[1][kt]), acc1, 0, 0, 0);
    }
    if (dt < 6) {
#pragma unroll
      for (int kt = 0; kt < 4; ++kt)
        a[dt & 1][kt] = *(const uint4*)(W1b + (size_t)((dt + 2) * 16 + lm) * CH
                                        + kt * 32 + q * 8);
    }
    const int d0 = dt * 16 + q * 4;
    float4 bi = *(const float4*)(b1 + d0);
    f32x4 aa[2] = {acc0, acc1};
#pragma unroll
    for (int nt = 0; nt < 2; ++nt) {
      ushort4 o;
      o.x = f2bf(fmaxf(aa[nt][0] + bi.x, 0.f));
      o.y = f2bf(fmaxf(aa[nt][1] + bi.y, 0.f));
      o.z = f2bf(fmaxf(aa[nt][2] + bi.z, 0.f));
      o.w = f2bf(fmaxf(aa[nt][3] + bi.w, 0.f));
      const int row = nt * 16 + lm;
      const int chunk = dt * 2 + (q >> 1);
      *(ushort4*)(Hs + row * 256 + ((chunk ^ (row & 7)) << 4) + ((q & 1) << 3)) = o;
    }
  }

  // ---- h D-layout -> B-fragments
  uint4 B2[2][4];
#pragma unroll
  for (int nt = 0; nt < 2; ++nt) {
    const int row = nt * 16 + lm;
#pragma unroll
    for (int kt = 0; kt < 4; ++kt)
      B2[nt][kt] = *(const uint4*)(Hs + row * 256 + (((kt * 4 + q) ^ (row & 7)) << 4));
  }

  // ---- contiguous h store
  {
    const int srow = lane >> 4, schk = lane & 15;
#pragma unroll
    for (int p = 0; p < 8; ++p) {
      const int row = p * 4 + srow;
      const int gnode = nw0 + row;
      uint4 vv = *(const uint4*)(Hs + row * 256 + ((schk ^ (row & 7)) << 4));
      if (gnode < NODES)
        *(uint4*)(h_t + ((size_t)b * NODES + gnode) * CH + schk * 8) = vv;
    }
  }

  // ---- phase 2: z = relu(Wp h + bp)
#pragma unroll
  for (int kt = 0; kt < 4; ++kt) {
    a[0][kt] = *(const uint4*)(Wpb + (size_t)(lm) * CH + kt * 32 + q * 8);
    a[1][kt] = *(const uint4*)(Wpb + (size_t)(16 + lm) * CH + kt * 32 + q * 8);
  }
#pragma unroll
  for (int dt = 0; dt < 8; ++dt) {
    f32x4 acc0 = (f32x4){0.f, 0.f, 0.f, 0.f};
    f32x4 acc1 = (f32x4){0.f, 0.f, 0.f, 0.f};
#pragma unroll
    for (int kt = 0; kt < 4; ++kt) {
      acc0 = __builtin_amdgcn_mfma_f32_16x16x32_bf16(
          asbf8(a[dt & 1][kt]), asbf8(B2[0][kt]), acc0, 0, 0, 0);
      acc1 = __builtin_amdgcn_mfma_f32_16x16x32_bf16(
          asbf8(a[dt & 1][kt]), asbf8(B2[1][kt]), acc1, 0, 0, 0);
    }
    if (dt < 6) {
#pragma unroll
      for (int kt = 0; kt < 4; ++kt)
        a[dt & 1][kt] = *(const uint4*)(Wpb + (size_t)((dt + 2) * 16 + lm) * CH
                                        + kt * 32 + q * 8);
    }
    const int d0 = dt * 16 + q * 4;
    float4 bi = *(const float4*)(bp + d0);
    f32x4 aa[2] = {acc0, acc1};
#pragma unroll
    for (int nt = 0; nt < 2; ++nt) {
      ushort4 o;
      o.x = f2bf(fmaxf(aa[nt][0] + bi.x, 0.f));
      o.y = f2bf(fmaxf(aa[nt][1] + bi.y, 0.f));
      o.z = f2bf(fmaxf(aa[nt][2] + bi.z, 0.f));
      o.w = f2bf(fmaxf(aa[nt][3] + bi.w, 0.f));
      const int row = nt * 16 + lm;
      const int chunk = dt * 2 + (q >> 1);
      *(ushort4*)(Hs + row * 256 + ((chunk ^ (row & 7)) << 4) + ((q & 1) << 3)) = o;
    }
  }

  // ---- contiguous z store
  {
    const int srow = lane >> 4, schk = lane & 15;
#pragma unroll
    for (int p = 0; p < 8; ++p) {
      const int row = p * 4 + srow;
      const int gnode = nw0 + row;
      uint4 vv = *(const uint4*)(Hs + row * 256 + ((schk ^ (row & 7)) << 4));
      if (gnode < NODES)
        *(uint4*)(z_t + ((size_t)b * NODES + gnode) * CH + schk * 8) = vv;
    }
  }
}

// ---------------------------------------------------------------------------
// gather_max: xj[b][n][c] = max_k z[b][idx[n,k]][c], packed-u16 bf16 max.
// PURE gather kernel: no LDS, no barriers, ~high occupancy. Each 16-lane
// group covers one node's full 256B row per load instruction; 16 neighbor
// loads in flight per lane before a 15-op pkmax tree. 16 nodes per block.
// b = bid&7 keeps each batch's 2.56MB z slab affine to one XCD L2.
// ---------------------------------------------------------------------------
__global__ __launch_bounds__(256) void gather_max(
    const unsigned short* __restrict__ z_t, const int* __restrict__ e0,
    unsigned short* __restrict__ xj_t)
{
  const int bid = blockIdx.x;
  const int b   = bid & 7;
  const int n0  = (bid >> 3) * 16;
  const int t   = threadIdx.x;
  const int wv  = t >> 6, lane = t & 63;
  const int r   = lane >> 4, c16 = lane & 15;

  const int n  = n0 + wv * 4 + r;
  const int gn = (n < NODES) ? n : (NODES - 1);

  // 16 neighbor indices (16-lane-uniform addresses -> broadcast loads)
  const int* ep = e0 + ((size_t)b * NODES + gn) * KNB;
  uint4 i0 = *(const uint4*)(ep);
  uint4 i1 = *(const uint4*)(ep + 4);
  uint4 i2 = *(const uint4*)(ep + 8);
  uint4 i3 = *(const uint4*)(ep + 12);
  unsigned jns[KNB] = {i0.x, i0.y, i0.z, i0.w, i1.x, i1.y, i1.z, i1.w,
                       i2.x, i2.y, i2.z, i2.w, i3.x, i3.y, i3.z, i3.w};

  const unsigned short* Zb = z_t + (size_t)b * NODES * CH;
  uint4 v[KNB];
#pragma unroll
  for (int k = 0; k < KNB; ++k)
    v[k] = *(const uint4*)(Zb + (size_t)jns[k] * CH + c16 * 8);

#pragma unroll
  for (int k = 0; k < 8; ++k) v[k] = pkmax4(v[k], v[k + 8]);
#pragma unroll
  for (int k = 0; k < 4; ++k) v[k] = pkmax4(v[k], v[k + 4]);
  v[0] = pkmax4(v[0], v[2]);
  v[1] = pkmax4(v[1], v[3]);
  v[0] = pkmax4(v[0], v[1]);

  if (n < NODES)
    *(uint4*)(xj_t + ((size_t)b * NODES + n) * CH + c16 * 8) = v[0];
}

// ---------------------------------------------------------------------------
// out[b][d][n] = relu(W2 @ [h[n]; xj[n]] + b2) — now a DENSE GEMM, both
// inputs node-major bf16. Staging is fully contiguous (1KB per instr),
// then the R6 MFMA sweep (one barrier, 4 waves x 64d x 64n, K=256).
// ---------------------------------------------------------------------------
__global__ __launch_bounds__(256) void out_gemm(
    const unsigned short* __restrict__ h_t, const unsigned short* __restrict__ xj_t,
    const unsigned short* __restrict__ W2b, const float* __restrict__ b2,
    float* __restrict__ out)
{
  const int bid = blockIdx.x;
  const int b   = bid & 7;
  const int n0  = (bid >> 3) * 64;
  const int t   = threadIdx.x;
  const int lane = t & 63, w = t >> 6;
  const int lm = lane & 15, q = lane >> 4;

  __shared__ __align__(16) unsigned short cat[64 * 256];  // 32 KB, swizzled
  char* catB = (char*)cat;

  // ---- stage h (chunks 0..15) and xj (chunks 16..31): contiguous reads
  {
    const int nl = t >> 4, c16 = t & 15;   // 16 rows per 256-thr pass
#pragma unroll
    for (int rep = 0; rep < 4; ++rep) {
      const int row = rep * 16 + nl;
      const int gn = (n0 + row < NODES) ? (n0 + row) : (NODES - 1);
      uint4 hv = *(const uint4*)(h_t + ((size_t)b * NODES + gn) * CH + c16 * 8);
      *(uint4*)(catB + row * 512 + ((c16 ^ (row & 7)) << 4)) = hv;
      uint4 xv = *(const uint4*)(xj_t + ((size_t)b * NODES + gn) * CH + c16 * 8);
      *(uint4*)(catB + row * 512 + (((16 + c16) ^ (row & 7)) << 4)) = xv;
    }
  }

  __syncthreads();

  // ---- MFMA sweep: wave w -> d in [64w, 64w+64), 64 nodes, K=256
  const int d0 = w * 64;
  f32x4 acc[4][4];
#pragma unroll
  for (int dt = 0; dt < 4; ++dt)
#pragma unroll
    for (int nt = 0; nt < 4; ++nt) acc[dt][nt] = (f32x4){0.f, 0.f, 0.f, 0.f};

  uint4 acur[4], anxt[4];
#pragma unroll
  for (int dt = 0; dt < 4; ++dt)
    acur[dt] = *(const uint4*)(W2b + (size_t)(d0 + dt * 16 + lm) * CO + q * 8);

#pragma unroll
  for (int kt = 0; kt < 8; ++kt) {
    if (kt < 7) {
#pragma unroll
      for (int dt = 0; dt < 4; ++dt)
        anxt[dt] = *(const uint4*)(W2b + (size_t)(d0 + dt * 16 + lm) * CO
                                   + (kt + 1) * 32 + q * 8);
    }
#pragma unroll
    for (int nt = 0; nt < 4; ++nt) {
      const int nl = nt * 16 + lm;
      const int chunk = kt * 4 + q;
      bf16x8 bb = asbf8(*(const uint4*)(catB + nl * 512 + ((chunk ^ (nl & 7)) << 4)));
#pragma unroll
      for (int dt = 0; dt < 4; ++dt)
        acc[dt][nt] = __builtin_amdgcn_mfma_f32_16x16x32_bf16(
            asbf8(acur[dt]), bb, acc[dt][nt], 0, 0, 0);
    }
#pragma unroll
    for (int dt = 0; dt < 4; ++dt) acur[dt] = anxt[dt];
  }

  // ---- epilogue: fp32 out [b][d][n]
#pragma unroll
  for (int dt = 0; dt < 4; ++dt) {
    const int dbase = d0 + dt * 16 + q * 4;
    float4 bi = *(const float4*)(b2 + dbase);
    float bv[4] = {bi.x, bi.y, bi.z, bi.w};
#pragma unroll
    for (int nt = 0; nt < 4; ++nt) {
      const int gn = n0 + nt * 16 + lm;
      if (gn < NODES) {
        float* op = out + (size_t)(b * CO + dbase) * NODES + gn;
#pragma unroll
        for (int r = 0; r < 4; ++r)
          op[(size_t)r * NODES] = fmaxf(acc[dt][nt][r] + bv[r], 0.f);
      }
    }
  }
}

// ---------------------------------------------------------------------------
extern "C" void kernel_launch(void* const* d_in, const int* in_sizes, int n_in,
                              void* d_out, int out_size, void* d_ws, size_t ws_size,
                              hipStream_t stream) {
  const float* x  = (const float*)d_in[0];
  const int*   ei = (const int*)d_in[1];   // (2,B,N,K); first half = targets
  const float* W1 = (const float*)d_in[2];
  const float* b1 = (const float*)d_in[3];
  const float* Wp = (const float*)d_in[4];
  const float* bp = (const float*)d_in[5];
  const float* W2 = (const float*)d_in[6];
  const float* b2 = (const float*)d_in[7];
  float* out = (float*)d_out;

  unsigned short* ws   = (unsigned short*)d_ws;
  unsigned short* h_t  = ws;                                   // [B][N][128] bf16
  unsigned short* z_t  = h_t  + (size_t)BATCH * NODES * CH;    // [B][N][128] bf16
  unsigned short* xj_t = z_t  + (size_t)BATCH * NODES * CH;    // [B][N][128] bf16
  unsigned short* W1b  = xj_t + (size_t)BATCH * NODES * CH;
  unsigned short* Wpb  = W1b + CH * CH;
  unsigned short* W2b  = Wpb + CH * CH;

  prep<<<96, 256, 0, stream>>>(W1, Wp, W2, W1b, Wpb, W2b);

  const int NTF = (NODES + 127) / 128;  // 79
  fused_hz<<<dim3(NTF, BATCH), 256, 0, stream>>>(W1b, b1, Wpb, bp, x, h_t, z_t);

  const int NTG = (NODES + 15) / 16;    // 625
  gather_max<<<BATCH * NTG, 256, 0, stream>>>(z_t, ei, xj_t);

  const int NTO = (NODES + 63) / 64;    // 157
  out_gemm<<<BATCH * NTO, 256, 0, stream>>>(h_t, xj_t, W2b, b2, out);
}